// Round 8
// baseline (756.753 us; speedup 1.0000x reference)
//
#include <hip/hip_runtime.h>
#include <float.h>

typedef _Float16 half8 __attribute__((ext_vector_type(8)));
typedef _Float16 half4v __attribute__((ext_vector_type(4)));
typedef float f32x4 __attribute__((ext_vector_type(4)));

#define M_TOTAL 16384
#define N_CODES 8192
#define KDIM    256
#define BM 128
#define BN 128
#define BK 64
#define NB (N_CODES / BN)   // 64 partials per query
#define TS 64               // LDS tile k-stride in halfs (BK)
#define MARGIN 3.0e-3f
#define SQ_SCALE 512.0f
#define SE_SCALE 2048.0f
#define INV_PROD 1.9073486328125e-06f   // 2/(512*2048) = 2^-19, exact
#define RC_CHUNK 256
#define RC_NCH (N_CODES / RC_CHUNK)     // 32 chunks per flagged query
#define RPB 2048                        // refine_partial grid
#define RM_BLOCKS 256

// ---------------------------------------------------------------------------
// Fused prep: fp32 -> fp16 (exact pow2 scale) + numpy-bit-exact sumsq.
// (verified r7)
// ---------------------------------------------------------------------------
__global__ void prep_kernel(const float* __restrict__ src, _Float16* __restrict__ dst,
                            float* __restrict__ sq, float scale) {
    const int tid = threadIdx.x;
    const int row0 = blockIdx.x * 4;
    {   // convert
        const int r = row0 + (tid >> 6);
        const int e4 = tid & 63;
        const float4 v = *(const float4*)(src + (size_t)r * KDIM + e4 * 4);
        const half4v h = {(_Float16)(v.x * scale), (_Float16)(v.y * scale),
                          (_Float16)(v.z * scale), (_Float16)(v.w * scale)};
        ((half4v*)(dst + (size_t)r * KDIM))[e4] = h;
    }
    if (tid < 64) {   // np-bit-exact sumsq, 4 rows on wave 0
        const int grp = tid >> 4;
        const int sub = tid & 15;
        const int row = row0 + grp;
        const float* p = src + (size_t)row * KDIM + (sub >> 3) * 128 + (sub & 7);
        float r;
        {
            #pragma clang fp contract(off)
            float v = p[0];
            r = v * v;
            #pragma unroll
            for (int k = 1; k < 16; k++) { const float w = p[k * 8]; r = r + w * w; }
        }
        const float t1 = r  + __shfl_xor(r,  1, 64);
        const float t2 = t1 + __shfl_xor(t1, 2, 64);
        const float t3 = t2 + __shfl_xor(t2, 4, 64);
        const float t4 = t3 + __shfl_xor(t3, 8, 64);
        if (sub == 0) sq[row] = t4;
    }
}

// ---------------------------------------------------------------------------
// MFMA approx-distance + packed-u32 top-2 partials. BK=64 (half the barriers
// of r7). LDS row = 64 halfs = 128 B = all 32 banks; XOR swizzle p = col ^
// (row&7): staging writes 1 word/bank/row (min), fragment reads 2-way (free).
// Comparator key (verified r7): d = fmaf(acc, -2^-19, e_sq + 8) packed with
// 7-bit local index in the low mantissa bits.
// ---------------------------------------------------------------------------
union SMemU {
    _Float16 t[2][BM * TS];                          // 2 x 16 KB
    struct { unsigned k1[BM][2]; unsigned k2[BM][2]; } red;
};

__global__ __launch_bounds__(256, 2)
void mfma_top2_kernel(const _Float16* __restrict__ Qh, const _Float16* __restrict__ Eh,
                      const float* __restrict__ esq,
                      unsigned* __restrict__ k1s, unsigned* __restrict__ k2s) {
    __shared__ SMemU sm;
    const int tid = threadIdx.x;
    const int m0 = blockIdx.x * BM;
    const int n0 = blockIdx.y * BN;
    const int w = tid >> 6, lane = tid & 63;
    const int wm = w >> 1, wn = w & 1;
    const int qd = lane >> 4, c = lane & 15;
    const int which = w >> 1, half = w & 1;
    const _Float16* src = (which == 0) ? (Qh + (size_t)(m0 + half * 64) * KDIM)
                                       : (Eh + (size_t)(n0 + half * 64) * KDIM);
    _Float16* dst = sm.t[which] + half * 64 * TS;

    f32x4 acc[4][4];
    const f32x4 zero = {0.f, 0.f, 0.f, 0.f};
    #pragma unroll
    for (int mt = 0; mt < 4; mt++)
        #pragma unroll
        for (int nt = 0; nt < 4; nt++) acc[mt][nt] = zero;

    const int csw = c & 7;   // read-side swizzle term (row&7 == c&7)

    for (int k0 = 0; k0 < KDIM; k0 += BK) {
        if (k0) __syncthreads();
        #pragma unroll
        for (int it = 0; it < 8; it++) {
            const int u = it * 64 + lane;
            const int row = u >> 3, col = u & 7;     // 64 rows x 8 col-blocks
            const half8 v = *(const half8*)(src + (size_t)row * KDIM + k0 + col * 8);
            *(half8*)(dst + row * TS + (col ^ (row & 7)) * 8) = v;
        }
        __syncthreads();
        #pragma unroll
        for (int kk = 0; kk < 2; kk++) {
            const int cb = kk * 4 + qd;              // logical col-block
            half8 qa[4];
            #pragma unroll
            for (int mt = 0; mt < 4; mt++) {
                const int r = wm * 64 + mt * 16 + c;
                qa[mt] = *(const half8*)(sm.t[0] + r * TS + (cb ^ csw) * 8);
            }
            #pragma unroll
            for (int nt = 0; nt < 4; nt++) {
                const int rn = wn * 64 + nt * 16 + c;
                const half8 eh = *(const half8*)(sm.t[1] + rn * TS + (cb ^ csw) * 8);
                #pragma unroll
                for (int mt = 0; mt < 4; mt++)
                    acc[mt][nt] = __builtin_amdgcn_mfma_f32_16x16x32_f16(qa[mt], eh, acc[mt][nt], 0, 0, 0);
            }
        }
    }

    // ---- epilogue: packed top-2 (verified r7) ----
    float es8[4];
    #pragma unroll
    for (int nt = 0; nt < 4; nt++) es8[nt] = esq[n0 + wn * 64 + nt * 16 + c] + 8.0f;

    unsigned k1[16], k2[16];
    #pragma unroll
    for (int i = 0; i < 16; i++) { k1[i] = 0xFFFFFFFFu; k2[i] = 0xFFFFFFFFu; }

    #pragma unroll
    for (int mt = 0; mt < 4; mt++)
        #pragma unroll
        for (int nt = 0; nt < 4; nt++) {
            const unsigned nl = (unsigned)(wn * 64 + nt * 16 + c);
            #pragma unroll
            for (int r = 0; r < 4; r++) {
                const int i = mt * 4 + r;
                const float d = fmaf(acc[mt][nt][r], -INV_PROD, es8[nt]);
                const unsigned k = (__float_as_uint(d) & 0xFFFFFF80u) | nl;
                const unsigned t = min(k1[i], k);
                k2[i] = min(k2[i], max(k1[i], k));
                k1[i] = t;
            }
        }
    #pragma unroll
    for (int s = 1; s < 16; s <<= 1) {
        #pragma unroll
        for (int i = 0; i < 16; i++) {
            const unsigned ok1 = (unsigned)__shfl_xor((int)k1[i], s, 64);
            const unsigned ok2 = (unsigned)__shfl_xor((int)k2[i], s, 64);
            const unsigned t = min(k1[i], ok1);
            k2[i] = min(min(k2[i], ok2), max(k1[i], ok1));
            k1[i] = t;
        }
    }
    __syncthreads();
    if (c == 0) {
        #pragma unroll
        for (int mt = 0; mt < 4; mt++)
            #pragma unroll
            for (int r = 0; r < 4; r++) {
                const int ml = wm * 64 + mt * 16 + qd * 4 + r;
                sm.red.k1[ml][wn] = k1[mt * 4 + r];
                sm.red.k2[ml][wn] = k2[mt * 4 + r];
            }
    }
    __syncthreads();
    if (tid < BM) {
        const unsigned a1 = sm.red.k1[tid][0], b1 = sm.red.k1[tid][1];
        const unsigned a2 = sm.red.k2[tid][0], b2 = sm.red.k2[tid][1];
        const size_t o = (size_t)(m0 + tid) * NB + blockIdx.y;
        k1s[o] = min(a1, b1);
        k2s[o] = min(min(a2, b2), max(a1, b1));
    }
}

// ---------------------------------------------------------------------------
// Merge 64 packed partials/query. Safe gap -> emit; narrow -> flag. (r7)
// ---------------------------------------------------------------------------
__global__ void finalize_kernel(const float* __restrict__ Q, const float* __restrict__ E,
                                const unsigned* __restrict__ k1s, const unsigned* __restrict__ k2s,
                                int* __restrict__ fcount, int* __restrict__ flist,
                                float* __restrict__ out) {
    const int q = blockIdx.x * 4 + (threadIdx.x >> 6);
    const int lane = threadIdx.x & 63;
    const unsigned k1 = k1s[(size_t)q * NB + lane];
    const unsigned k2 = k2s[(size_t)q * NB + lane];
    float v1 = __uint_as_float(k1 & 0xFFFFFF80u);
    int   gi = lane * 128 + (int)(k1 & 127u);
    float v2 = __uint_as_float(k2 & 0xFFFFFF80u);
    #pragma unroll
    for (int s = 1; s < 64; s <<= 1) {
        const float ov1 = __shfl_xor(v1, s, 64);
        const int   ogi = __shfl_xor(gi, s, 64);
        const float ov2 = __shfl_xor(v2, s, 64);
        const float nv2 = fminf(fminf(v2, ov2), fmaxf(v1, ov1));
        const bool take = (ov1 < v1) || (ov1 == v1 && ogi < gi);
        v1 = take ? ov1 : v1;
        gi = take ? ogi : gi;
        v2 = nv2;
    }
    if ((v2 - v1) < MARGIN) {
        if (lane == 0) flist[atomicAdd(fcount, 1)] = q;
        return;
    }

    if (lane == 0) out[q] = (float)gi;
    const float4 qv = *(const float4*)(Q + (size_t)q * KDIM + lane * 4);
    const float4 ev = *(const float4*)(E + (size_t)gi * KDIM + lane * 4);
    float4 st;
    {
        #pragma clang fp contract(off)
        st.x = qv.x + (ev.x - qv.x);
        st.y = qv.y + (ev.y - qv.y);
        st.z = qv.z + (ev.z - qv.z);
        st.w = qv.w + (ev.w - qv.w);
    }
    *(float4*)(out + M_TOTAL + (size_t)q * KDIM + lane * 4) = st;

    const float dx = qv.x - ev.x, dy = qv.y - ev.y, dz = qv.z - ev.z, dw = qv.w - ev.w;
    float s = dx * dx + dy * dy + dz * dz + dw * dw;
    #pragma unroll
    for (int off = 32; off > 0; off >>= 1) s += __shfl_down(s, off);
    if (lane == 0)
        atomicAdd(out + M_TOTAL + (size_t)M_TOTAL * KDIM,
                  s * (1.25f / (float)((size_t)M_TOTAL * KDIM)));
}

// ---------------------------------------------------------------------------
// Refine phase 1: block task = (flagged query, 256-code chunk); one THREAD
// per code. Q row in LDS (broadcast reads); 4 independent FMA chains per
// thread (deterministic, ~1e-7 accurate); one block-reduce at the end.
// ---------------------------------------------------------------------------
__global__ __launch_bounds__(256, 4)
void refine_partial_kernel(const float* __restrict__ Q, const float* __restrict__ E,
                           const float* __restrict__ qsq, const float* __restrict__ esq,
                           const int* __restrict__ fcount, const int* __restrict__ flist,
                           float* __restrict__ rp_v, int* __restrict__ rp_i) {
    const int cnt = *fcount;
    const int ntasks = cnt * RC_NCH;
    const int tid = threadIdx.x;
    const int wid = tid >> 6, lane = tid & 63;
    __shared__ float qs[KDIM];
    __shared__ float rv[4];
    __shared__ int   ri[4];

    for (int t = blockIdx.x; t < ntasks; t += RPB) {
        const int fi = t >> 5;              // / RC_NCH
        const int chunk = t & (RC_NCH - 1);
        const int q = flist[fi];
        __syncthreads();                    // protect qs/rv reuse across iterations
        qs[tid] = Q[(size_t)q * KDIM + tid];
        __syncthreads();
        const float qsv = qsq[q];
        const int n = chunk * RC_CHUNK + tid;
        const float* e = E + (size_t)n * KDIM;

        float ax = 0.f, ay = 0.f, az = 0.f, aw = 0.f;
        #pragma unroll 8
        for (int k = 0; k < KDIM / 4; k++) {
            const float4 ev = ((const float4*)e)[k];
            const float4 qv = ((const float4*)qs)[k];
            ax = fmaf(qv.x, ev.x, ax);
            ay = fmaf(qv.y, ev.y, ay);
            az = fmaf(qv.z, ev.z, az);
            aw = fmaf(qv.w, ev.w, aw);
        }
        const float p = (ax + ay) + (az + aw);
        float d;
        {
            #pragma clang fp contract(off)
            const float t1 = qsv + esq[n];
            d = t1 - 2.0f * p;
        }
        // block argmin, lexicographic (d, n); n strictly increases with tid
        float bv = d; int bi = n;
        #pragma unroll
        for (int s = 1; s < 64; s <<= 1) {
            const float ov = __shfl_xor(bv, s, 64);
            const int   oi = __shfl_xor(bi, s, 64);
            if (ov < bv || (ov == bv && oi < bi)) { bv = ov; bi = oi; }
        }
        if (lane == 0) { rv[wid] = bv; ri[wid] = bi; }
        __syncthreads();
        if (tid == 0) {
            float fv = rv[0]; int fidx = ri[0];
            #pragma unroll
            for (int u = 1; u < 4; u++) {
                if (rv[u] < fv || (rv[u] == fv && ri[u] < fidx)) { fv = rv[u]; fidx = ri[u]; }
            }
            rp_v[t] = fv; rp_i[t] = fidx;
        }
    }
}

// ---------------------------------------------------------------------------
// Refine phase 2: reduce 32 chunk partials per flagged query; emit outputs.
// ---------------------------------------------------------------------------
__global__ void refine_merge_kernel(const float* __restrict__ Q, const float* __restrict__ E,
                                    const int* __restrict__ fcount, const int* __restrict__ flist,
                                    const float* __restrict__ rp_v, const int* __restrict__ rp_i,
                                    float* __restrict__ out) {
    const int cnt = *fcount;
    const int lane = threadIdx.x;
    for (int fi = blockIdx.x; fi < cnt; fi += RM_BLOCKS) {
        const int q = flist[fi];
        float bv = FLT_MAX; int bi = 0x7fffffff;
        if (lane < RC_NCH) {
            bv = rp_v[(size_t)fi * RC_NCH + lane];
            bi = rp_i[(size_t)fi * RC_NCH + lane];
        }
        #pragma unroll
        for (int s = 1; s < 64; s <<= 1) {
            const float ov = __shfl_xor(bv, s, 64);
            const int   oi = __shfl_xor(bi, s, 64);
            if (ov < bv || (ov == bv && oi < bi)) { bv = ov; bi = oi; }
        }
        if (lane == 0) out[q] = (float)bi;

        const float4 qv = *(const float4*)(Q + (size_t)q * KDIM + lane * 4);
        const float4 ev = *(const float4*)(E + (size_t)bi * KDIM + lane * 4);
        float4 st;
        {
            #pragma clang fp contract(off)
            st.x = qv.x + (ev.x - qv.x);
            st.y = qv.y + (ev.y - qv.y);
            st.z = qv.z + (ev.z - qv.z);
            st.w = qv.w + (ev.w - qv.w);
        }
        *(float4*)(out + M_TOTAL + (size_t)q * KDIM + lane * 4) = st;
        const float dx = qv.x - ev.x, dy = qv.y - ev.y, dz = qv.z - ev.z, dw = qv.w - ev.w;
        float s = dx * dx + dy * dy + dz * dz + dw * dw;
        #pragma unroll
        for (int off = 32; off > 0; off >>= 1) s += __shfl_down(s, off);
        if (lane == 0)
            atomicAdd(out + M_TOTAL + (size_t)M_TOTAL * KDIM,
                      s * (1.25f / (float)((size_t)M_TOTAL * KDIM)));
    }
}

extern "C" void kernel_launch(void* const* d_in, const int* in_sizes, int n_in,
                              void* d_out, int out_size, void* d_ws, size_t ws_size,
                              hipStream_t stream) {
    const float* Q = (const float*)d_in[0];   // [16,1024,256] fp32
    const float* E = (const float*)d_in[1];   // [8192,256] fp32
    float* out = (float*)d_out;               // [16384 idx][4194304 quantized][1 loss]

    char* ws = (char*)d_ws;
    _Float16* Qh  = (_Float16*)(ws);                                 // 0..8 MB
    _Float16* Eh  = (_Float16*)(ws + (size_t)8  * 1024 * 1024);      // 8..12 MB
    float* qsq    = (float*)   (ws + (size_t)12 * 1024 * 1024);      // 64 KB
    float* esq    = qsq + M_TOTAL;                                   // 32 KB
    unsigned* k1s = (unsigned*)(ws + (size_t)13 * 1024 * 1024);      // 4 MB
    unsigned* k2s = (unsigned*)(ws + (size_t)17 * 1024 * 1024);      // 4 MB
    int*   fcount = (int*)     (ws + (size_t)25 * 1024 * 1024);      // 4 B
    int*   flist  = fcount + 64;                                     // 64 KB
    // refine partials alias k1s/k2s (finalize consumed them; stream-ordered)
    float* rp_v   = (float*)k1s;
    int*   rp_i   = (int*)k2s;

    hipMemsetAsync(out + M_TOTAL + (size_t)M_TOTAL * KDIM, 0, sizeof(float), stream);
    hipMemsetAsync(fcount, 0, sizeof(int), stream);

    prep_kernel<<<M_TOTAL / 4, 256, 0, stream>>>(Q, Qh, qsq, SQ_SCALE);
    prep_kernel<<<N_CODES / 4, 256, 0, stream>>>(E, Eh, esq, SE_SCALE);

    mfma_top2_kernel<<<dim3(M_TOTAL / BM, N_CODES / BN), 256, 0, stream>>>(
        Qh, Eh, esq, k1s, k2s);

    finalize_kernel<<<M_TOTAL / 4, 256, 0, stream>>>(Q, E, k1s, k2s, fcount, flist, out);
    refine_partial_kernel<<<RPB, 256, 0, stream>>>(Q, E, qsq, esq, fcount, flist, rp_v, rp_i);
    refine_merge_kernel<<<RM_BLOCKS, 64, 0, stream>>>(Q, E, fcount, flist, rp_v, rp_i, out);
}

// Round 9
// 536.008 us; speedup vs baseline: 1.4118x; 1.4118x over previous
//
#include <hip/hip_runtime.h>
#include <float.h>

typedef _Float16 half8 __attribute__((ext_vector_type(8)));
typedef _Float16 half4v __attribute__((ext_vector_type(4)));
typedef float f32x4 __attribute__((ext_vector_type(4)));

#define M_TOTAL 16384
#define N_CODES 8192
#define KDIM    256
#define BM 128
#define BN 128
#define BK 64
#define NB (N_CODES / BN)   // 64 partials per query
#define TS 64               // LDS tile k-stride in halfs (BK)
#define MARGIN 3.0e-3f
#define SQ_SCALE 512.0f
#define SE_SCALE 2048.0f
#define INV_PROD 1.9073486328125e-06f   // 2/(512*2048) = 2^-19, exact
#define RG 4                 // flagged queries per refine group
#define RCODES 1024          // codes per refine chunk-task
#define RNCH (N_CODES / RCODES)  // 8 chunks
#define RPB 1024             // refine_partial grid
#define RM_BLOCKS 256

// ---------------------------------------------------------------------------
// Fused prep: fp32 -> fp16 (exact pow2 scale) + numpy-bit-exact sumsq (r7/r8).
// ---------------------------------------------------------------------------
__global__ void prep_kernel(const float* __restrict__ src, _Float16* __restrict__ dst,
                            float* __restrict__ sq, float scale) {
    const int tid = threadIdx.x;
    const int row0 = blockIdx.x * 4;
    {   // convert
        const int r = row0 + (tid >> 6);
        const int e4 = tid & 63;
        const float4 v = *(const float4*)(src + (size_t)r * KDIM + e4 * 4);
        const half4v h = {(_Float16)(v.x * scale), (_Float16)(v.y * scale),
                          (_Float16)(v.z * scale), (_Float16)(v.w * scale)};
        ((half4v*)(dst + (size_t)r * KDIM))[e4] = h;
    }
    if (tid < 64) {   // np-bit-exact sumsq, 4 rows on wave 0
        const int grp = tid >> 4;
        const int sub = tid & 15;
        const int row = row0 + grp;
        const float* p = src + (size_t)row * KDIM + (sub >> 3) * 128 + (sub & 7);
        float r;
        {
            #pragma clang fp contract(off)
            float v = p[0];
            r = v * v;
            #pragma unroll
            for (int k = 1; k < 16; k++) { const float w = p[k * 8]; r = r + w * w; }
        }
        const float t1 = r  + __shfl_xor(r,  1, 64);
        const float t2 = t1 + __shfl_xor(t1, 2, 64);
        const float t3 = t2 + __shfl_xor(t2, 4, 64);
        const float t4 = t3 + __shfl_xor(t3, 8, 64);
        if (sub == 0) sq[row] = t4;
    }
}

// ---------------------------------------------------------------------------
// E transpose: ET[k][n] = E[n][k]  (fp32, for coalesced refine scans).
// 64x64 tiles via LDS, stride 65 (conflict-free both phases).
// ---------------------------------------------------------------------------
__global__ void transpose_kernel(const float* __restrict__ E, float* __restrict__ ET) {
    __shared__ float tile[64][65];
    const int n0 = blockIdx.x * 64;
    const int k0 = blockIdx.y * 64;
    const int tid = threadIdx.x;
    const int r = tid >> 4;          // 0..15
    const int c4 = tid & 15;
    #pragma unroll
    for (int p = 0; p < 4; p++) {
        const int row = p * 16 + r;
        const float4 v = *(const float4*)(E + (size_t)(n0 + row) * KDIM + k0 + c4 * 4);
        tile[row][c4 * 4 + 0] = v.x;
        tile[row][c4 * 4 + 1] = v.y;
        tile[row][c4 * 4 + 2] = v.z;
        tile[row][c4 * 4 + 3] = v.w;
    }
    __syncthreads();
    #pragma unroll
    for (int p = 0; p < 4; p++) {
        const int d = p * 16 + r;
        float4 o;
        o.x = tile[c4 * 4 + 0][d];
        o.y = tile[c4 * 4 + 1][d];
        o.z = tile[c4 * 4 + 2][d];
        o.w = tile[c4 * 4 + 3][d];
        *(float4*)(ET + (size_t)(k0 + d) * N_CODES + n0 + c4 * 4) = o;
    }
}

// ---------------------------------------------------------------------------
// MFMA approx-distance + packed-u32 top-2 partials (verified r8, unchanged).
// ---------------------------------------------------------------------------
union SMemU {
    _Float16 t[2][BM * TS];
    struct { unsigned k1[BM][2]; unsigned k2[BM][2]; } red;
};

__global__ __launch_bounds__(256, 2)
void mfma_top2_kernel(const _Float16* __restrict__ Qh, const _Float16* __restrict__ Eh,
                      const float* __restrict__ esq,
                      unsigned* __restrict__ k1s, unsigned* __restrict__ k2s) {
    __shared__ SMemU sm;
    const int tid = threadIdx.x;
    const int m0 = blockIdx.x * BM;
    const int n0 = blockIdx.y * BN;
    const int w = tid >> 6, lane = tid & 63;
    const int wm = w >> 1, wn = w & 1;
    const int qd = lane >> 4, c = lane & 15;
    const int which = w >> 1, half = w & 1;
    const _Float16* src = (which == 0) ? (Qh + (size_t)(m0 + half * 64) * KDIM)
                                       : (Eh + (size_t)(n0 + half * 64) * KDIM);
    _Float16* dst = sm.t[which] + half * 64 * TS;

    f32x4 acc[4][4];
    const f32x4 zero = {0.f, 0.f, 0.f, 0.f};
    #pragma unroll
    for (int mt = 0; mt < 4; mt++)
        #pragma unroll
        for (int nt = 0; nt < 4; nt++) acc[mt][nt] = zero;

    const int csw = c & 7;

    for (int k0 = 0; k0 < KDIM; k0 += BK) {
        if (k0) __syncthreads();
        #pragma unroll
        for (int it = 0; it < 8; it++) {
            const int u = it * 64 + lane;
            const int row = u >> 3, col = u & 7;
            const half8 v = *(const half8*)(src + (size_t)row * KDIM + k0 + col * 8);
            *(half8*)(dst + row * TS + (col ^ (row & 7)) * 8) = v;
        }
        __syncthreads();
        #pragma unroll
        for (int kk = 0; kk < 2; kk++) {
            const int cb = kk * 4 + qd;
            half8 qa[4];
            #pragma unroll
            for (int mt = 0; mt < 4; mt++) {
                const int r = wm * 64 + mt * 16 + c;
                qa[mt] = *(const half8*)(sm.t[0] + r * TS + (cb ^ csw) * 8);
            }
            #pragma unroll
            for (int nt = 0; nt < 4; nt++) {
                const int rn = wn * 64 + nt * 16 + c;
                const half8 eh = *(const half8*)(sm.t[1] + rn * TS + (cb ^ csw) * 8);
                #pragma unroll
                for (int mt = 0; mt < 4; mt++)
                    acc[mt][nt] = __builtin_amdgcn_mfma_f32_16x16x32_f16(qa[mt], eh, acc[mt][nt], 0, 0, 0);
            }
        }
    }

    float es8[4];
    #pragma unroll
    for (int nt = 0; nt < 4; nt++) es8[nt] = esq[n0 + wn * 64 + nt * 16 + c] + 8.0f;

    unsigned k1[16], k2[16];
    #pragma unroll
    for (int i = 0; i < 16; i++) { k1[i] = 0xFFFFFFFFu; k2[i] = 0xFFFFFFFFu; }

    #pragma unroll
    for (int mt = 0; mt < 4; mt++)
        #pragma unroll
        for (int nt = 0; nt < 4; nt++) {
            const unsigned nl = (unsigned)(wn * 64 + nt * 16 + c);
            #pragma unroll
            for (int r = 0; r < 4; r++) {
                const int i = mt * 4 + r;
                const float d = fmaf(acc[mt][nt][r], -INV_PROD, es8[nt]);
                const unsigned k = (__float_as_uint(d) & 0xFFFFFF80u) | nl;
                const unsigned t = min(k1[i], k);
                k2[i] = min(k2[i], max(k1[i], k));
                k1[i] = t;
            }
        }
    #pragma unroll
    for (int s = 1; s < 16; s <<= 1) {
        #pragma unroll
        for (int i = 0; i < 16; i++) {
            const unsigned ok1 = (unsigned)__shfl_xor((int)k1[i], s, 64);
            const unsigned ok2 = (unsigned)__shfl_xor((int)k2[i], s, 64);
            const unsigned t = min(k1[i], ok1);
            k2[i] = min(min(k2[i], ok2), max(k1[i], ok1));
            k1[i] = t;
        }
    }
    __syncthreads();
    if (c == 0) {
        #pragma unroll
        for (int mt = 0; mt < 4; mt++)
            #pragma unroll
            for (int r = 0; r < 4; r++) {
                const int ml = wm * 64 + mt * 16 + qd * 4 + r;
                sm.red.k1[ml][wn] = k1[mt * 4 + r];
                sm.red.k2[ml][wn] = k2[mt * 4 + r];
            }
    }
    __syncthreads();
    if (tid < BM) {
        const unsigned a1 = sm.red.k1[tid][0], b1 = sm.red.k1[tid][1];
        const unsigned a2 = sm.red.k2[tid][0], b2 = sm.red.k2[tid][1];
        const size_t o = (size_t)(m0 + tid) * NB + blockIdx.y;
        k1s[o] = min(a1, b1);
        k2s[o] = min(min(a2, b2), max(a1, b1));
    }
}

// ---------------------------------------------------------------------------
// Merge 64 packed partials/query. Safe gap -> emit; narrow -> flag. (r7/r8)
// ---------------------------------------------------------------------------
__global__ void finalize_kernel(const float* __restrict__ Q, const float* __restrict__ E,
                                const unsigned* __restrict__ k1s, const unsigned* __restrict__ k2s,
                                int* __restrict__ fcount, int* __restrict__ flist,
                                float* __restrict__ out) {
    const int q = blockIdx.x * 4 + (threadIdx.x >> 6);
    const int lane = threadIdx.x & 63;
    const unsigned k1 = k1s[(size_t)q * NB + lane];
    const unsigned k2 = k2s[(size_t)q * NB + lane];
    float v1 = __uint_as_float(k1 & 0xFFFFFF80u);
    int   gi = lane * 128 + (int)(k1 & 127u);
    float v2 = __uint_as_float(k2 & 0xFFFFFF80u);
    #pragma unroll
    for (int s = 1; s < 64; s <<= 1) {
        const float ov1 = __shfl_xor(v1, s, 64);
        const int   ogi = __shfl_xor(gi, s, 64);
        const float ov2 = __shfl_xor(v2, s, 64);
        const float nv2 = fminf(fminf(v2, ov2), fmaxf(v1, ov1));
        const bool take = (ov1 < v1) || (ov1 == v1 && ogi < gi);
        v1 = take ? ov1 : v1;
        gi = take ? ogi : gi;
        v2 = nv2;
    }
    if ((v2 - v1) < MARGIN) {
        if (lane == 0) flist[atomicAdd(fcount, 1)] = q;
        return;
    }

    if (lane == 0) out[q] = (float)gi;
    const float4 qv = *(const float4*)(Q + (size_t)q * KDIM + lane * 4);
    const float4 ev = *(const float4*)(E + (size_t)gi * KDIM + lane * 4);
    float4 st;
    {
        #pragma clang fp contract(off)
        st.x = qv.x + (ev.x - qv.x);
        st.y = qv.y + (ev.y - qv.y);
        st.z = qv.z + (ev.z - qv.z);
        st.w = qv.w + (ev.w - qv.w);
    }
    *(float4*)(out + M_TOTAL + (size_t)q * KDIM + lane * 4) = st;

    const float dx = qv.x - ev.x, dy = qv.y - ev.y, dz = qv.z - ev.z, dw = qv.w - ev.w;
    float s = dx * dx + dy * dy + dz * dz + dw * dw;
    #pragma unroll
    for (int off = 32; off > 0; off >>= 1) s += __shfl_down(s, off);
    if (lane == 0)
        atomicAdd(out + M_TOTAL + (size_t)M_TOTAL * KDIM,
                  s * (1.25f / (float)((size_t)M_TOTAL * KDIM)));
}

// ---------------------------------------------------------------------------
// Refine phase 1 (v3): block task = (group of 4 flagged queries, 1024-code
// chunk). Coalesced ET reads (64 lanes x 16B contiguous), 16 independent FMA
// chains/thread, one block-reduce per (g). Exact fp32 two-step-rounded
// distances; strict-< over ascending n => first occurrence.
// ---------------------------------------------------------------------------
__global__ __launch_bounds__(256, 4)
void refine_partial_kernel(const float* __restrict__ Q, const float* __restrict__ ET,
                           const float* __restrict__ qsq, const float* __restrict__ esq,
                           const int* __restrict__ fcount, const int* __restrict__ flist,
                           float* __restrict__ rp_v, int* __restrict__ rp_i) {
    const int cnt = *fcount;
    if (cnt == 0) return;
    const int ngroups = (cnt + RG - 1) / RG;
    const int ntasks = ngroups * RNCH;
    const int tid = threadIdx.x;
    const int w = tid >> 6, lane = tid & 63;
    __shared__ float qs[RG][KDIM];
    __shared__ float redv[4][RG];
    __shared__ int   redi[4][RG];

    for (int t = blockIdx.x; t < ntasks; t += RPB) {
        const int grp = t >> 3;             // / RNCH
        const int chunk = t & (RNCH - 1);
        __syncthreads();                    // protect qs/red reuse
        {
            const int g = tid >> 6, c4 = tid & 63;
            const int fi = min(grp * RG + g, cnt - 1);   // clamp: dup work, never read
            const int q = flist[fi];
            *(float4*)&qs[g][c4 * 4] = *(const float4*)(Q + (size_t)q * KDIM + c4 * 4);
        }
        __syncthreads();

        const int nb = chunk * RCODES + tid * 4;   // this thread's 4 codes
        float a[RG][4];
        #pragma unroll
        for (int g = 0; g < RG; g++)
            #pragma unroll
            for (int j = 0; j < 4; j++) a[g][j] = 0.f;

        for (int k4 = 0; k4 < KDIM / 4; k4++) {
            float4 qv[RG];
            #pragma unroll
            for (int g = 0; g < RG; g++) qv[g] = *(const float4*)&qs[g][k4 * 4];
            #pragma unroll
            for (int kk = 0; kk < 4; kk++) {
                const float4 ev = *(const float4*)(ET + (size_t)(k4 * 4 + kk) * N_CODES + nb);
                #pragma unroll
                for (int g = 0; g < RG; g++) {
                    const float qk = (kk == 0) ? qv[g].x : (kk == 1) ? qv[g].y
                                   : (kk == 2) ? qv[g].z : qv[g].w;
                    a[g][0] = fmaf(qk, ev.x, a[g][0]);
                    a[g][1] = fmaf(qk, ev.y, a[g][1]);
                    a[g][2] = fmaf(qk, ev.z, a[g][2]);
                    a[g][3] = fmaf(qk, ev.w, a[g][3]);
                }
            }
        }

        float es[4];
        #pragma unroll
        for (int j = 0; j < 4; j++) es[j] = esq[nb + j];

        #pragma unroll
        for (int g = 0; g < RG; g++) {
            const int fi = min(grp * RG + g, cnt - 1);
            const float qsv = qsq[flist[fi]];
            float bv = FLT_MAX; int bi = 0x7fffffff;
            #pragma unroll
            for (int j = 0; j < 4; j++) {
                float d;
                {
                    #pragma clang fp contract(off)
                    const float t1 = qsv + es[j];
                    d = t1 - 2.0f * a[g][j];
                }
                if (d < bv) { bv = d; bi = nb + j; }   // ascending n
            }
            #pragma unroll
            for (int s = 1; s < 64; s <<= 1) {
                const float ov = __shfl_xor(bv, s, 64);
                const int   oi = __shfl_xor(bi, s, 64);
                if (ov < bv || (ov == bv && oi < bi)) { bv = ov; bi = oi; }
            }
            if (lane == 0) { redv[w][g] = bv; redi[w][g] = bi; }
        }
        __syncthreads();
        if (tid < RG) {
            float fv = redv[0][tid]; int fidx = redi[0][tid];
            #pragma unroll
            for (int u = 1; u < 4; u++) {
                if (redv[u][tid] < fv || (redv[u][tid] == fv && redi[u][tid] < fidx)) {
                    fv = redv[u][tid]; fidx = redi[u][tid];
                }
            }
            rp_v[(size_t)t * RG + tid] = fv;
            rp_i[(size_t)t * RG + tid] = fidx;
        }
    }
}

// ---------------------------------------------------------------------------
// Refine phase 2: reduce 8 chunk partials per flagged query; emit outputs.
// ---------------------------------------------------------------------------
__global__ void refine_merge_kernel(const float* __restrict__ Q, const float* __restrict__ E,
                                    const int* __restrict__ fcount, const int* __restrict__ flist,
                                    const float* __restrict__ rp_v, const int* __restrict__ rp_i,
                                    float* __restrict__ out) {
    const int cnt = *fcount;
    const int lane = threadIdx.x;
    for (int fi = blockIdx.x; fi < cnt; fi += RM_BLOCKS) {
        const int q = flist[fi];
        const int grp = fi >> 2, g = fi & 3;
        float bv = FLT_MAX; int bi = 0x7fffffff;
        if (lane < RNCH) {
            const size_t t = (size_t)(grp * RNCH + lane);
            bv = rp_v[t * RG + g];
            bi = rp_i[t * RG + g];
        }
        #pragma unroll
        for (int s = 1; s < 64; s <<= 1) {
            const float ov = __shfl_xor(bv, s, 64);
            const int   oi = __shfl_xor(bi, s, 64);
            if (ov < bv || (ov == bv && oi < bi)) { bv = ov; bi = oi; }
        }
        if (lane == 0) out[q] = (float)bi;

        const float4 qv = *(const float4*)(Q + (size_t)q * KDIM + lane * 4);
        const float4 ev = *(const float4*)(E + (size_t)bi * KDIM + lane * 4);
        float4 st;
        {
            #pragma clang fp contract(off)
            st.x = qv.x + (ev.x - qv.x);
            st.y = qv.y + (ev.y - qv.y);
            st.z = qv.z + (ev.z - qv.z);
            st.w = qv.w + (ev.w - qv.w);
        }
        *(float4*)(out + M_TOTAL + (size_t)q * KDIM + lane * 4) = st;
        const float dx = qv.x - ev.x, dy = qv.y - ev.y, dz = qv.z - ev.z, dw = qv.w - ev.w;
        float s = dx * dx + dy * dy + dz * dz + dw * dw;
        #pragma unroll
        for (int off = 32; off > 0; off >>= 1) s += __shfl_down(s, off);
        if (lane == 0)
            atomicAdd(out + M_TOTAL + (size_t)M_TOTAL * KDIM,
                      s * (1.25f / (float)((size_t)M_TOTAL * KDIM)));
    }
}

extern "C" void kernel_launch(void* const* d_in, const int* in_sizes, int n_in,
                              void* d_out, int out_size, void* d_ws, size_t ws_size,
                              hipStream_t stream) {
    const float* Q = (const float*)d_in[0];   // [16,1024,256] fp32
    const float* E = (const float*)d_in[1];   // [8192,256] fp32
    float* out = (float*)d_out;               // [16384 idx][4194304 quantized][1 loss]

    char* ws = (char*)d_ws;
    _Float16* Qh  = (_Float16*)(ws);                                 // 0..8 MB
    _Float16* Eh  = (_Float16*)(ws + (size_t)8  * 1024 * 1024);      // 8..12 MB
    float* qsq    = (float*)   (ws + (size_t)12 * 1024 * 1024);      // 64 KB
    float* esq    = qsq + M_TOTAL;                                   // 32 KB
    unsigned* k1s = (unsigned*)(ws + (size_t)13 * 1024 * 1024);      // 4 MB
    unsigned* k2s = (unsigned*)(ws + (size_t)17 * 1024 * 1024);      // 4 MB
    int*   fcount = (int*)     (ws + (size_t)25 * 1024 * 1024);      // 4 B
    int*   flist  = fcount + 64;                                     // 64 KB
    float* ET     = (float*)   (ws + (size_t)26 * 1024 * 1024);      // 8 MB (26..34)
    // refine partials alias k1s/k2s (finalize consumed them; stream-ordered)
    float* rp_v   = (float*)k1s;
    int*   rp_i   = (int*)k2s;

    hipMemsetAsync(out + M_TOTAL + (size_t)M_TOTAL * KDIM, 0, sizeof(float), stream);
    hipMemsetAsync(fcount, 0, sizeof(int), stream);

    prep_kernel<<<M_TOTAL / 4, 256, 0, stream>>>(Q, Qh, qsq, SQ_SCALE);
    prep_kernel<<<N_CODES / 4, 256, 0, stream>>>(E, Eh, esq, SE_SCALE);
    transpose_kernel<<<dim3(N_CODES / 64, KDIM / 64), 256, 0, stream>>>(E, ET);

    mfma_top2_kernel<<<dim3(M_TOTAL / BM, N_CODES / BN), 256, 0, stream>>>(
        Qh, Eh, esq, k1s, k2s);

    finalize_kernel<<<M_TOTAL / 4, 256, 0, stream>>>(Q, E, k1s, k2s, fcount, flist, out);
    refine_partial_kernel<<<RPB, 256, 0, stream>>>(Q, ET, qsq, esq, fcount, flist, rp_v, rp_i);
    refine_merge_kernel<<<RM_BLOCKS, 64, 0, stream>>>(Q, E, fcount, flist, rp_v, rp_i, out);
}

// Round 10
// 244.486 us; speedup vs baseline: 3.0953x; 2.1924x over previous
//
#include <hip/hip_runtime.h>
#include <float.h>

typedef _Float16 half8 __attribute__((ext_vector_type(8)));
typedef _Float16 half4v __attribute__((ext_vector_type(4)));
typedef float f32x4 __attribute__((ext_vector_type(4)));

#define M_TOTAL 16384
#define N_CODES 8192
#define KDIM    256
#define BM 128
#define BN 128
#define BK 32
#define NK (KDIM / BK)      // 8 k-iterations
#define NB (N_CODES / BN)   // 64 partials per query
#define TS 32               // LDS tile k-stride in halfs
#define MARGIN 3.0e-3f
#define SQ_SCALE 512.0f
#define SE_SCALE 2048.0f
#define INV_PROD 1.9073486328125e-06f   // 2/(512*2048) = 2^-19, exact
#define RG 4                 // flagged queries per refine group
#define RCODES 1024          // codes per refine chunk-task
#define RNCH (N_CODES / RCODES)  // 8 chunks
#define RPB 1024             // refine_partial grid
#define RM_BLOCKS 256
#define LR_BLOCKS 32         // loss_reduce grid

// ---------------------------------------------------------------------------
// Fused prep: fp32 -> fp16 (exact pow2 scale) + numpy-bit-exact sumsq (r7-r9).
// ---------------------------------------------------------------------------
__global__ void prep_kernel(const float* __restrict__ src, _Float16* __restrict__ dst,
                            float* __restrict__ sq, float scale) {
    const int tid = threadIdx.x;
    const int row0 = blockIdx.x * 4;
    {   // convert
        const int r = row0 + (tid >> 6);
        const int e4 = tid & 63;
        const float4 v = *(const float4*)(src + (size_t)r * KDIM + e4 * 4);
        const half4v h = {(_Float16)(v.x * scale), (_Float16)(v.y * scale),
                          (_Float16)(v.z * scale), (_Float16)(v.w * scale)};
        ((half4v*)(dst + (size_t)r * KDIM))[e4] = h;
    }
    if (tid < 64) {   // np-bit-exact sumsq, 4 rows on wave 0
        const int grp = tid >> 4;
        const int sub = tid & 15;
        const int row = row0 + grp;
        const float* p = src + (size_t)row * KDIM + (sub >> 3) * 128 + (sub & 7);
        float r;
        {
            #pragma clang fp contract(off)
            float v = p[0];
            r = v * v;
            #pragma unroll
            for (int k = 1; k < 16; k++) { const float w = p[k * 8]; r = r + w * w; }
        }
        const float t1 = r  + __shfl_xor(r,  1, 64);
        const float t2 = t1 + __shfl_xor(t1, 2, 64);
        const float t3 = t2 + __shfl_xor(t2, 4, 64);
        const float t4 = t3 + __shfl_xor(t3, 8, 64);
        if (sub == 0) sq[row] = t4;
    }
}

// ---------------------------------------------------------------------------
// E transpose (r9): ET[k][n] = E[n][k], 64x64 LDS tiles, stride 65.
// ---------------------------------------------------------------------------
__global__ void transpose_kernel(const float* __restrict__ E, float* __restrict__ ET) {
    __shared__ float tile[64][65];
    const int n0 = blockIdx.x * 64;
    const int k0 = blockIdx.y * 64;
    const int tid = threadIdx.x;
    const int r = tid >> 4;
    const int c4 = tid & 15;
    #pragma unroll
    for (int p = 0; p < 4; p++) {
        const int row = p * 16 + r;
        const float4 v = *(const float4*)(E + (size_t)(n0 + row) * KDIM + k0 + c4 * 4);
        tile[row][c4 * 4 + 0] = v.x;
        tile[row][c4 * 4 + 1] = v.y;
        tile[row][c4 * 4 + 2] = v.z;
        tile[row][c4 * 4 + 3] = v.w;
    }
    __syncthreads();
    #pragma unroll
    for (int p = 0; p < 4; p++) {
        const int d = p * 16 + r;
        float4 o;
        o.x = tile[c4 * 4 + 0][d];
        o.y = tile[c4 * 4 + 1][d];
        o.z = tile[c4 * 4 + 2][d];
        o.w = tile[c4 * 4 + 3][d];
        *(float4*)(ET + (size_t)(k0 + d) * N_CODES + n0 + c4 * 4) = o;
    }
}

// ---------------------------------------------------------------------------
// MFMA approx-distance + packed-u32 top-2 partials, v3:
// BK=32, DOUBLE-BUFFERED LDS + register prefetch -> one barrier per k-iter,
// global-load latency off the critical path. Swizzle & comparator = r7
// (verified). d = fmaf(acc, -2^-19, e_sq + 8); key = (bits & ~127) | local_n.
// ---------------------------------------------------------------------------
union SMemU {
    _Float16 t[2][2][BM * TS];                       // [buf][which(Q/E)] : 2x16 KB
    struct { unsigned k1[BM][2]; unsigned k2[BM][2]; } red;
};

__global__ __launch_bounds__(256, 2)
void mfma_top2_kernel(const _Float16* __restrict__ Qh, const _Float16* __restrict__ Eh,
                      const float* __restrict__ esq,
                      unsigned* __restrict__ k1s, unsigned* __restrict__ k2s) {
    __shared__ SMemU sm;
    const int tid = threadIdx.x;
    const int m0 = blockIdx.x * BM;
    const int n0 = blockIdx.y * BN;
    const int w = tid >> 6, lane = tid & 63;
    const int wm = w >> 1, wn = w & 1;
    const int qd = lane >> 4, c = lane & 15;
    const int which = w >> 1, half = w & 1;
    const _Float16* src = (which == 0) ? (Qh + (size_t)(m0 + half * 64) * KDIM)
                                       : (Eh + (size_t)(n0 + half * 64) * KDIM);
    const int hofs = half * 64 * TS;

    // per-thread staging coordinates (4 issues x 64 lanes = 64 rows x 4 cols)
    int srow[4], scol[4];
    #pragma unroll
    for (int it = 0; it < 4; it++) {
        const int u = it * 64 + lane;
        srow[it] = u >> 2;
        scol[it] = u & 3;
    }

    f32x4 acc[4][4];
    const f32x4 zero = {0.f, 0.f, 0.f, 0.f};
    #pragma unroll
    for (int mt = 0; mt < 4; mt++)
        #pragma unroll
        for (int nt = 0; nt < 4; nt++) acc[mt][nt] = zero;

    const int csw = (c >> 1) & 3;   // read-side swizzle ((row>>1)&3 == (c>>1)&3)

    half8 pf[4];
    // prologue: k-iter 0 -> regs -> buf0
    #pragma unroll
    for (int it = 0; it < 4; it++)
        pf[it] = *(const half8*)(src + (size_t)srow[it] * KDIM + scol[it] * 8);
    {
        _Float16* d0 = sm.t[0][which] + hofs;
        #pragma unroll
        for (int it = 0; it < 4; it++)
            *(half8*)(d0 + srow[it] * TS + (scol[it] ^ ((srow[it] >> 1) & 3)) * 8) = pf[it];
    }
    __syncthreads();

    for (int ki = 0; ki < NK; ki++) {
        if (ki + 1 < NK) {
            const int k0 = (ki + 1) * BK;
            #pragma unroll
            for (int it = 0; it < 4; it++)
                pf[it] = *(const half8*)(src + (size_t)srow[it] * KDIM + k0 + scol[it] * 8);
        }
        // compute on buf ki&1
        const _Float16* bq = sm.t[ki & 1][0];
        const _Float16* be = sm.t[ki & 1][1];
        half8 qa[4];
        #pragma unroll
        for (int mt = 0; mt < 4; mt++)
            qa[mt] = *(const half8*)(bq + (wm * 64 + mt * 16 + c) * TS + (qd ^ csw) * 8);
        #pragma unroll
        for (int nt = 0; nt < 4; nt++) {
            const half8 eh = *(const half8*)(be + (wn * 64 + nt * 16 + c) * TS + (qd ^ csw) * 8);
            #pragma unroll
            for (int mt = 0; mt < 4; mt++)
                acc[mt][nt] = __builtin_amdgcn_mfma_f32_16x16x32_f16(qa[mt], eh, acc[mt][nt], 0, 0, 0);
        }
        if (ki + 1 < NK) {
            _Float16* dn = sm.t[(ki + 1) & 1][which] + hofs;
            #pragma unroll
            for (int it = 0; it < 4; it++)
                *(half8*)(dn + srow[it] * TS + (scol[it] ^ ((srow[it] >> 1) & 3)) * 8) = pf[it];
            __syncthreads();   // single barrier per iteration
        }
    }

    // ---- epilogue: packed top-2 (verified r7-r9) ----
    float es8[4];
    #pragma unroll
    for (int nt = 0; nt < 4; nt++) es8[nt] = esq[n0 + wn * 64 + nt * 16 + c] + 8.0f;

    unsigned k1[16], k2[16];
    #pragma unroll
    for (int i = 0; i < 16; i++) { k1[i] = 0xFFFFFFFFu; k2[i] = 0xFFFFFFFFu; }

    #pragma unroll
    for (int mt = 0; mt < 4; mt++)
        #pragma unroll
        for (int nt = 0; nt < 4; nt++) {
            const unsigned nl = (unsigned)(wn * 64 + nt * 16 + c);
            #pragma unroll
            for (int r = 0; r < 4; r++) {
                const int i = mt * 4 + r;
                const float d = fmaf(acc[mt][nt][r], -INV_PROD, es8[nt]);
                const unsigned k = (__float_as_uint(d) & 0xFFFFFF80u) | nl;
                const unsigned t = min(k1[i], k);
                k2[i] = min(k2[i], max(k1[i], k));
                k1[i] = t;
            }
        }
    #pragma unroll
    for (int s = 1; s < 16; s <<= 1) {
        #pragma unroll
        for (int i = 0; i < 16; i++) {
            const unsigned ok1 = (unsigned)__shfl_xor((int)k1[i], s, 64);
            const unsigned ok2 = (unsigned)__shfl_xor((int)k2[i], s, 64);
            const unsigned t = min(k1[i], ok1);
            k2[i] = min(min(k2[i], ok2), max(k1[i], ok1));
            k1[i] = t;
        }
    }
    __syncthreads();
    if (c == 0) {
        #pragma unroll
        for (int mt = 0; mt < 4; mt++)
            #pragma unroll
            for (int r = 0; r < 4; r++) {
                const int ml = wm * 64 + mt * 16 + qd * 4 + r;
                sm.red.k1[ml][wn] = k1[mt * 4 + r];
                sm.red.k2[ml][wn] = k2[mt * 4 + r];
            }
    }
    __syncthreads();
    if (tid < BM) {
        const unsigned a1 = sm.red.k1[tid][0], b1 = sm.red.k1[tid][1];
        const unsigned a2 = sm.red.k2[tid][0], b2 = sm.red.k2[tid][1];
        const size_t o = (size_t)(m0 + tid) * NB + blockIdx.y;
        k1s[o] = min(a1, b1);
        k2s[o] = min(min(a2, b2), max(a1, b1));
    }
}

// ---------------------------------------------------------------------------
// Merge 64 packed partials/query. Safe gap -> emit winner + gather; loss term
// goes to ws_loss[q] (NO contended atomic). Narrow gap -> flag.
// ---------------------------------------------------------------------------
__global__ void finalize_kernel(const float* __restrict__ Q, const float* __restrict__ E,
                                const unsigned* __restrict__ k1s, const unsigned* __restrict__ k2s,
                                int* __restrict__ fcount, int* __restrict__ flist,
                                float* __restrict__ ws_loss, float* __restrict__ out) {
    const int q = blockIdx.x * 4 + (threadIdx.x >> 6);
    const int lane = threadIdx.x & 63;
    const unsigned k1 = k1s[(size_t)q * NB + lane];
    const unsigned k2 = k2s[(size_t)q * NB + lane];
    float v1 = __uint_as_float(k1 & 0xFFFFFF80u);
    int   gi = lane * 128 + (int)(k1 & 127u);
    float v2 = __uint_as_float(k2 & 0xFFFFFF80u);
    #pragma unroll
    for (int s = 1; s < 64; s <<= 1) {
        const float ov1 = __shfl_xor(v1, s, 64);
        const int   ogi = __shfl_xor(gi, s, 64);
        const float ov2 = __shfl_xor(v2, s, 64);
        const float nv2 = fminf(fminf(v2, ov2), fmaxf(v1, ov1));
        const bool take = (ov1 < v1) || (ov1 == v1 && ogi < gi);
        v1 = take ? ov1 : v1;
        gi = take ? ogi : gi;
        v2 = nv2;
    }
    if ((v2 - v1) < MARGIN) {
        if (lane == 0) flist[atomicAdd(fcount, 1)] = q;
        return;   // refine path writes out[q], ST row, and ws_loss[q]
    }

    if (lane == 0) out[q] = (float)gi;
    const float4 qv = *(const float4*)(Q + (size_t)q * KDIM + lane * 4);
    const float4 ev = *(const float4*)(E + (size_t)gi * KDIM + lane * 4);
    float4 st;
    {
        #pragma clang fp contract(off)
        st.x = qv.x + (ev.x - qv.x);
        st.y = qv.y + (ev.y - qv.y);
        st.z = qv.z + (ev.z - qv.z);
        st.w = qv.w + (ev.w - qv.w);
    }
    *(float4*)(out + M_TOTAL + (size_t)q * KDIM + lane * 4) = st;

    const float dx = qv.x - ev.x, dy = qv.y - ev.y, dz = qv.z - ev.z, dw = qv.w - ev.w;
    float s = dx * dx + dy * dy + dz * dz + dw * dw;
    #pragma unroll
    for (int off = 32; off > 0; off >>= 1) s += __shfl_down(s, off);
    if (lane == 0) ws_loss[q] = s;
}

// ---------------------------------------------------------------------------
// Refine phase 1 (r9, verified): group of RG flagged queries x 1024-code
// chunk; coalesced ET reads; exact fp32 two-step-rounded distances.
// ---------------------------------------------------------------------------
__global__ __launch_bounds__(256, 4)
void refine_partial_kernel(const float* __restrict__ Q, const float* __restrict__ ET,
                           const float* __restrict__ qsq, const float* __restrict__ esq,
                           const int* __restrict__ fcount, const int* __restrict__ flist,
                           float* __restrict__ rp_v, int* __restrict__ rp_i) {
    const int cnt = *fcount;
    if (cnt == 0) return;
    const int ngroups = (cnt + RG - 1) / RG;
    const int ntasks = ngroups * RNCH;
    const int tid = threadIdx.x;
    const int w = tid >> 6, lane = tid & 63;
    __shared__ float qs[RG][KDIM];
    __shared__ float redv[4][RG];
    __shared__ int   redi[4][RG];

    for (int t = blockIdx.x; t < ntasks; t += RPB) {
        const int grp = t >> 3;
        const int chunk = t & (RNCH - 1);
        __syncthreads();
        {
            const int g = tid >> 6, c4 = tid & 63;
            const int fi = min(grp * RG + g, cnt - 1);
            const int q = flist[fi];
            *(float4*)&qs[g][c4 * 4] = *(const float4*)(Q + (size_t)q * KDIM + c4 * 4);
        }
        __syncthreads();

        const int nb = chunk * RCODES + tid * 4;
        float a[RG][4];
        #pragma unroll
        for (int g = 0; g < RG; g++)
            #pragma unroll
            for (int j = 0; j < 4; j++) a[g][j] = 0.f;

        for (int k4 = 0; k4 < KDIM / 4; k4++) {
            float4 qv[RG];
            #pragma unroll
            for (int g = 0; g < RG; g++) qv[g] = *(const float4*)&qs[g][k4 * 4];
            #pragma unroll
            for (int kk = 0; kk < 4; kk++) {
                const float4 ev = *(const float4*)(ET + (size_t)(k4 * 4 + kk) * N_CODES + nb);
                #pragma unroll
                for (int g = 0; g < RG; g++) {
                    const float qk = (kk == 0) ? qv[g].x : (kk == 1) ? qv[g].y
                                   : (kk == 2) ? qv[g].z : qv[g].w;
                    a[g][0] = fmaf(qk, ev.x, a[g][0]);
                    a[g][1] = fmaf(qk, ev.y, a[g][1]);
                    a[g][2] = fmaf(qk, ev.z, a[g][2]);
                    a[g][3] = fmaf(qk, ev.w, a[g][3]);
                }
            }
        }

        float es[4];
        #pragma unroll
        for (int j = 0; j < 4; j++) es[j] = esq[nb + j];

        #pragma unroll
        for (int g = 0; g < RG; g++) {
            const int fi = min(grp * RG + g, cnt - 1);
            const float qsv = qsq[flist[fi]];
            float bv = FLT_MAX; int bi = 0x7fffffff;
            #pragma unroll
            for (int j = 0; j < 4; j++) {
                float d;
                {
                    #pragma clang fp contract(off)
                    const float t1 = qsv + es[j];
                    d = t1 - 2.0f * a[g][j];
                }
                if (d < bv) { bv = d; bi = nb + j; }
            }
            #pragma unroll
            for (int s = 1; s < 64; s <<= 1) {
                const float ov = __shfl_xor(bv, s, 64);
                const int   oi = __shfl_xor(bi, s, 64);
                if (ov < bv || (ov == bv && oi < bi)) { bv = ov; bi = oi; }
            }
            if (lane == 0) { redv[w][g] = bv; redi[w][g] = bi; }
        }
        __syncthreads();
        if (tid < RG) {
            float fv = redv[0][tid]; int fidx = redi[0][tid];
            #pragma unroll
            for (int u = 1; u < 4; u++) {
                if (redv[u][tid] < fv || (redv[u][tid] == fv && redi[u][tid] < fidx)) {
                    fv = redv[u][tid]; fidx = redi[u][tid];
                }
            }
            rp_v[(size_t)t * RG + tid] = fv;
            rp_i[(size_t)t * RG + tid] = fidx;
        }
    }
}

// ---------------------------------------------------------------------------
// Refine phase 2: reduce 8 chunk partials per flagged query; emit outputs;
// loss term -> ws_loss[q].
// ---------------------------------------------------------------------------
__global__ void refine_merge_kernel(const float* __restrict__ Q, const float* __restrict__ E,
                                    const int* __restrict__ fcount, const int* __restrict__ flist,
                                    const float* __restrict__ rp_v, const int* __restrict__ rp_i,
                                    float* __restrict__ ws_loss, float* __restrict__ out) {
    const int cnt = *fcount;
    const int lane = threadIdx.x;
    for (int fi = blockIdx.x; fi < cnt; fi += RM_BLOCKS) {
        const int q = flist[fi];
        const int grp = fi >> 2, g = fi & 3;
        float bv = FLT_MAX; int bi = 0x7fffffff;
        if (lane < RNCH) {
            const size_t t = (size_t)(grp * RNCH + lane);
            bv = rp_v[t * RG + g];
            bi = rp_i[t * RG + g];
        }
        #pragma unroll
        for (int s = 1; s < 64; s <<= 1) {
            const float ov = __shfl_xor(bv, s, 64);
            const int   oi = __shfl_xor(bi, s, 64);
            if (ov < bv || (ov == bv && oi < bi)) { bv = ov; bi = oi; }
        }
        if (lane == 0) out[q] = (float)bi;

        const float4 qv = *(const float4*)(Q + (size_t)q * KDIM + lane * 4);
        const float4 ev = *(const float4*)(E + (size_t)bi * KDIM + lane * 4);
        float4 st;
        {
            #pragma clang fp contract(off)
            st.x = qv.x + (ev.x - qv.x);
            st.y = qv.y + (ev.y - qv.y);
            st.z = qv.z + (ev.z - qv.z);
            st.w = qv.w + (ev.w - qv.w);
        }
        *(float4*)(out + M_TOTAL + (size_t)q * KDIM + lane * 4) = st;
        const float dx = qv.x - ev.x, dy = qv.y - ev.y, dz = qv.z - ev.z, dw = qv.w - ev.w;
        float s = dx * dx + dy * dy + dz * dz + dw * dw;
        #pragma unroll
        for (int off = 32; off > 0; off >>= 1) s += __shfl_down(s, off);
        if (lane == 0) ws_loss[q] = s;
    }
}

// ---------------------------------------------------------------------------
// Loss reduction: sum ws_loss[0..M), scale, one atomic per block (32 total).
// ---------------------------------------------------------------------------
__global__ void loss_reduce_kernel(const float* __restrict__ ws_loss, float* __restrict__ out) {
    const int tid = threadIdx.x;
    float s = 0.f;
    for (int i = blockIdx.x * 256 + tid; i < M_TOTAL; i += LR_BLOCKS * 256)
        s += ws_loss[i];
    #pragma unroll
    for (int off = 32; off > 0; off >>= 1) s += __shfl_down(s, off);
    __shared__ float ws[4];
    if ((tid & 63) == 0) ws[tid >> 6] = s;
    __syncthreads();
    if (tid == 0) {
        const float tot = (ws[0] + ws[1]) + (ws[2] + ws[3]);
        atomicAdd(out + M_TOTAL + (size_t)M_TOTAL * KDIM,
                  tot * (1.25f / (float)((size_t)M_TOTAL * KDIM)));
    }
}

extern "C" void kernel_launch(void* const* d_in, const int* in_sizes, int n_in,
                              void* d_out, int out_size, void* d_ws, size_t ws_size,
                              hipStream_t stream) {
    const float* Q = (const float*)d_in[0];   // [16,1024,256] fp32
    const float* E = (const float*)d_in[1];   // [8192,256] fp32
    float* out = (float*)d_out;               // [16384 idx][4194304 quantized][1 loss]

    char* ws = (char*)d_ws;
    _Float16* Qh  = (_Float16*)(ws);                                 // 0..8 MB
    _Float16* Eh  = (_Float16*)(ws + (size_t)8  * 1024 * 1024);      // 8..12 MB
    float* qsq    = (float*)   (ws + (size_t)12 * 1024 * 1024);      // 64 KB
    float* esq    = qsq + M_TOTAL;                                   // 32 KB
    unsigned* k1s = (unsigned*)(ws + (size_t)13 * 1024 * 1024);      // 4 MB
    unsigned* k2s = (unsigned*)(ws + (size_t)17 * 1024 * 1024);      // 4 MB
    int*   fcount = (int*)     (ws + (size_t)25 * 1024 * 1024);      // 4 B
    int*   flist  = fcount + 64;                                     // 64 KB
    float* ws_loss= (float*)   (ws + (size_t)25 * 1024 * 1024 + 512 * 1024);  // 64 KB
    float* ET     = (float*)   (ws + (size_t)26 * 1024 * 1024);      // 8 MB
    // refine partials alias k1s/k2s (finalize consumed them; stream-ordered)
    float* rp_v   = (float*)k1s;
    int*   rp_i   = (int*)k2s;

    hipMemsetAsync(out + M_TOTAL + (size_t)M_TOTAL * KDIM, 0, sizeof(float), stream);
    hipMemsetAsync(fcount, 0, sizeof(int), stream);

    prep_kernel<<<M_TOTAL / 4, 256, 0, stream>>>(Q, Qh, qsq, SQ_SCALE);
    prep_kernel<<<N_CODES / 4, 256, 0, stream>>>(E, Eh, esq, SE_SCALE);
    transpose_kernel<<<dim3(N_CODES / 64, KDIM / 64), 256, 0, stream>>>(E, ET);

    mfma_top2_kernel<<<dim3(M_TOTAL / BM, N_CODES / BN), 256, 0, stream>>>(
        Qh, Eh, esq, k1s, k2s);

    finalize_kernel<<<M_TOTAL / 4, 256, 0, stream>>>(Q, E, k1s, k2s, fcount, flist, ws_loss, out);
    refine_partial_kernel<<<RPB, 256, 0, stream>>>(Q, ET, qsq, esq, fcount, flist, rp_v, rp_i);
    refine_merge_kernel<<<RM_BLOCKS, 64, 0, stream>>>(Q, E, fcount, flist, rp_v, rp_i, ws_loss, out);
    loss_reduce_kernel<<<LR_BLOCKS, 256, 0, stream>>>(ws_loss, out);
}